// Round 16
// baseline (89.514 us; speedup 1.0000x reference)
//
#include <hip/hip_runtime.h>
#include <math.h>

#define DM    1024
#define DQK   128
#define BATCH 4
#define SEQ   4096
// 1/sqrt(128) * log2(e) folded into Wq/bq at wcvt time -> softmax uses exp2 directly
#define QSCALE (0.08838834764831845f * 1.4426950408889634f)
#define DEFER_THR 6.0f

typedef _Float16 f16;
typedef _Float16 f16x4 __attribute__((ext_vector_type(4)));
typedef _Float16 f16x8 __attribute__((ext_vector_type(8)));
typedef float    f32x4 __attribute__((ext_vector_type(4)));

__device__ __forceinline__ void stage16(const void* g, unsigned char* l) {
    __builtin_amdgcn_global_load_lds(
        (const __attribute__((address_space(1))) unsigned int*)g,
        (__attribute__((address_space(3))) unsigned int*)l, 16, 0, 0);
}

// ---------------- W convert/transpose pre-kernel: fragment-linear output ----------------
__global__ __launch_bounds__(256) void wcvt_kernel(
    const float* __restrict__ Wq, const float* __restrict__ bq,
    const float* __restrict__ Wk, const float* __restrict__ bk,
    const float* __restrict__ Wv, const float* __restrict__ bv,
    f16* __restrict__ wt, float* __restrict__ biasf)
{
    const int sel   = blockIdx.x >> 5;          // 0..2
    const int rem   = blockIdx.x & 31;
    const int k0    = (rem >> 2) * 128;         // 0..896
    const int n0    = (rem & 3) * 32;           // 0..96
    const float* W; const float* b; float sc;
    if (sel == 0)      { W = Wq; b = bq; sc = QSCALE; }
    else if (sel == 1) { W = Wk; b = bk; sc = 1.0f; }
    else               { W = Wv; b = bv; sc = 1.0f; }

    __shared__ f16 tile[128][40];   // stride 80 B: column reads hit 8 distinct bank groups

    #pragma unroll
    for (int it = 0; it < 16; ++it) {
        int flat = threadIdx.x + it * 256;   // 0..4095
        int kk   = flat >> 5;                 // 0..127
        int cc   = flat & 31;                 // 0..31
        tile[kk][cc] = (f16)(W[(size_t)(k0 + kk) * DQK + n0 + cc] * sc);
    }
    __syncthreads();

    #pragma unroll
    for (int it = 0; it < 2; ++it) {
        int flat  = threadIdx.x + it * 256;   // 0..511
        int nl    = flat >> 4;                 // 0..31
        int kc    = flat & 15;                 // 0..15
        f16x8 v;
        #pragma unroll
        for (int i = 0; i < 8; ++i) v[i] = tile[kc * 8 + i][nl];
        const int N  = sel * 128 + n0 + nl;
        const int NF = N >> 4;
        const int c2 = N & 15;
        const int KS = (k0 >> 5) + (kc >> 2);
        const int gg = kc & 3;
        *(f16x8*)(wt + (size_t)(NF * 32 + KS) * 512 + c2 * 32 + gg * 8) = v;
    }
    if (rem == 0 && threadIdx.x < 128)
        biasf[sel * 128 + threadIdx.x] = b[threadIdx.x] * sc;
}

// ---------------- Fused QKV projection: frag-linear W direct from L2 ----------------
__global__ __launch_bounds__(512, 4) void proj_kernel(
    const float* __restrict__ x, const f16* __restrict__ wt2,
    const float* __restrict__ biasf,
    f16* __restrict__ qo, f16* __restrict__ ko, f16* __restrict__ vto)
{
    __shared__ __align__(16) unsigned char smem[50176];   // 2x8KB x-bufs; reused as 64x392 tile

    const int tid  = threadIdx.x;
    const int lane = tid & 63;
    const int w    = tid >> 6;
    const int c    = lane & 15;
    const int g    = lane >> 4;
    const int r0   = blockIdx.x * 64;

    const int srow = tid >> 3;
    const int skq  = tid & 7;
    const float* const xsrc  = x + (size_t)(r0 + srow) * DM + skq * 8;
    const unsigned     swoff = (unsigned)(srow * 128 + ((skq ^ (srow & 7)) * 16));

    const f16* const wl = wt2 + (size_t)(w * 3) * 32 * 512 + c * 32 + g * 8;

    f32x4 acc[4][3];
    #pragma unroll
    for (int rf = 0; rf < 4; ++rf)
        #pragma unroll
        for (int nf = 0; nf < 3; ++nf) acc[rf][nf] = (f32x4)0.f;

    float4 xa, xb2;
    auto gload = [&](int t) {
        const float* p = xsrc + t * 64;
        xa  = *(const float4*)p;
        xb2 = *(const float4*)(p + 4);
    };
    auto swrite = [&](int buf) {
        f16x8 h;
        h[0] = (f16)xa.x;  h[1] = (f16)xa.y;  h[2] = (f16)xa.z;  h[3] = (f16)xa.w;
        h[4] = (f16)xb2.x; h[5] = (f16)xb2.y; h[6] = (f16)xb2.z; h[7] = (f16)xb2.w;
        *(f16x8*)(smem + (unsigned)buf * 8192u + swoff) = h;
    };

    f16x8 bA[6], bB[6];

    gload(0); swrite(0);
    gload(1);
    #pragma unroll
    for (int nf = 0; nf < 3; ++nf)
        #pragma unroll
        for (int ks = 0; ks < 2; ++ks)
            bA[nf * 2 + ks] = *(const f16x8*)(wl + nf * 16384 + ks * 512);
    __syncthreads();   // x(0) visible

#define PROJ_ITER(TT, BUSE, BPRE)                                                         \
    {                                                                                     \
        const int cur = (TT) & 1;                                                         \
        if ((TT) < 15) swrite(cur ^ 1);                                                   \
        if ((TT) < 14) gload((TT) + 2);                                                   \
        if ((TT) < 15) {                                                                  \
            _Pragma("unroll")                                                             \
            for (int nf = 0; nf < 3; ++nf)                                                \
                _Pragma("unroll")                                                         \
                for (int ks = 0; ks < 2; ++ks)                                            \
                    BPRE[nf * 2 + ks] = *(const f16x8*)(wl + nf * 16384                   \
                                                        + (((TT) + 1) * 2 + ks) * 512);  \
        }                                                                                 \
        _Pragma("unroll")                                                                 \
        for (int rf = 0; rf < 4; ++rf) {                                                  \
            f16x8 af0 = *(const f16x8*)(smem + (unsigned)cur * 8192u                      \
                + (unsigned)((rf * 16 + c) * 128)                                         \
                + (unsigned)(((g) ^ (c & 7)) * 16));                                      \
            f16x8 af1 = *(const f16x8*)(smem + (unsigned)cur * 8192u                      \
                + (unsigned)((rf * 16 + c) * 128)                                         \
                + (unsigned)((((4 + g) ^ (c & 7)) * 16)));                                \
            _Pragma("unroll")                                                             \
            for (int nf = 0; nf < 3; ++nf) {                                              \
                acc[rf][nf] = __builtin_amdgcn_mfma_f32_16x16x32_f16(                     \
                    af0, BUSE[nf * 2 + 0], acc[rf][nf], 0, 0, 0);                         \
                acc[rf][nf] = __builtin_amdgcn_mfma_f32_16x16x32_f16(                     \
                    af1, BUSE[nf * 2 + 1], acc[rf][nf], 0, 0, 0);                         \
            }                                                                             \
        }                                                                                 \
        __syncthreads();                                                                  \
    }

    for (int t = 0; t < 16; t += 2) {
        PROJ_ITER(t,     bA, bB);
        PROJ_ITER(t + 1, bB, bA);
    }
#undef PROJ_ITER

    // ---- epilogue: bias + f16, bounce through LDS tile [64][392] for coalesced stores ----
    f16* const tile = (f16*)smem;
    #pragma unroll
    for (int rf = 0; rf < 4; ++rf)
        #pragma unroll
        for (int nf = 0; nf < 3; ++nf) {
            const int n  = w * 48 + nf * 16 + c;
            const float bb = biasf[n];
            #pragma unroll
            for (int r = 0; r < 4; ++r) {
                const int row = rf * 16 + 4 * g + r;
                tile[row * 392 + n] = (f16)(acc[rf][nf][r] + bb);
            }
        }
    __syncthreads();

    #pragma unroll
    for (int it = 0; it < 2; ++it) {
        const int u   = tid + it * 512;
        const int row = u >> 4;
        const int c8  = (u & 15) * 8;
        *(f16x8*)(qo + (size_t)(r0 + row) * DQK + c8) = *(const f16x8*)&tile[row * 392 + c8];
        *(f16x8*)(ko + (size_t)(r0 + row) * DQK + c8) = *(const f16x8*)&tile[row * 392 + 128 + c8];
    }
    const int gb = r0 >> 12;
    const int s0 = r0 & (SEQ - 1);
    #pragma unroll
    for (int it = 0; it < 2; ++it) {
        const int u  = tid + it * 512;
        const int d  = u >> 3;
        const int s8 = (u & 7) * 8;
        f16x8 vv;
        #pragma unroll
        for (int i = 0; i < 8; ++i) vv[i] = tile[(s8 + i) * 392 + 256 + d];
        *(f16x8*)(vto + ((size_t)gb * DQK + d) * SEQ + s0 + s8) = vv;
    }
}

// ---------------- Flash attention: round-4 winner + hoisted V-frag register loads --------
#define KOFF 0u
#define VOFF 65536u
#define POFF 131072u
#define MOFF 151552u
#define LOFF 152576u

__global__ __launch_bounds__(512, 2) void attn_kernel(
    const f16* __restrict__ qg, const f16* __restrict__ kg,
    const f16* __restrict__ vtg, float* __restrict__ out)
{
    __shared__ __align__(16) unsigned char smem[153600];

    const int tid  = threadIdx.x;
    const int lane = tid & 63;
    const int w    = tid >> 6;      // 0..7
    const int wq   = w >> 2;        // 0..1
    const int wk   = w & 3;         // 0..3
    const int c    = lane & 15;
    const int g    = lane >> 4;     // 0..3

    const int bid = blockIdx.x;
    const int xcd = bid & 7;
    const int bb  = xcd >> 1;
    const int qt  = (bid >> 3) | ((xcd & 1) << 5);
    const int q0  = qt * 64;

    const f16*  qb = qg  + (size_t)bb * SEQ * DQK;
    const char* kB = (const char*)(kg  + (size_t)bb * SEQ * DQK);
    const char* vB = (const char*)(vtg + (size_t)bb * DQK * SEQ);

    // Q frags (B-operand for swapped QK^T): q = 16n + c, k(d) = ks*32 + 8g + i
    f16x8 qf[2][4];
    {
        const f16* qr = qb + (size_t)(q0 + wq * 32) * DQK;
        #pragma unroll
        for (int n = 0; n < 2; ++n)
            #pragma unroll
            for (int ks = 0; ks < 4; ++ks)
                qf[n][ks] = *(const f16x8*)(qr + (n * 16 + c) * DQK + ks * 32 + 8 * g);
    }

    f32x4 o[2][9];   // [n (q-frag)][d-frag 0..7, 8 = ones column = running l]
    #pragma unroll
    for (int n = 0; n < 2; ++n)
        #pragma unroll
        for (int f = 0; f < 9; ++f) o[n][f] = (f32x4)0.f;
    float m_run[2] = {-3e38f, -3e38f};   // S^T domain: q = 16n + c

    f16x8 onesf;
    #pragma unroll
    for (int i = 0; i < 8; ++i) onesf[i] = (f16)1.0f;

    const unsigned wbase = (unsigned)(tid >> 6) * 1024;

    auto stage_tiles = [&](int t, int pbuf) {
        const int kv0 = t * 128;
        unsigned char* kdst = smem + KOFF + (unsigned)pbuf * 32768u + wbase;
        unsigned char* vdst = smem + VOFF + (unsigned)pbuf * 32768u + wbase;
        #pragma unroll
        for (int cc = 0; cc < 4; ++cc) {
            const int j   = tid + cc * 512;
            const int row = j >> 4;
            const int col = j & 15;
            const int sw  = (col ^ (row & 7)) * 16;
            stage16(kB + (size_t)(kv0 + row) * 256 + sw, kdst + cc * 8192);
            stage16(vB + (size_t)row * 8192 + (size_t)kv0 * 2 + sw, vdst + cc * 8192);
        }
    };

    stage_tiles(0, 0);
    __syncthreads();

    unsigned char* const pmine = smem + POFF + (unsigned)w * 2560u;

    for (int t = 0; t < 32; ++t) {
        const int pb = t & 1;
        if (t < 31) stage_tiles(t + 1, pb ^ 1);

        unsigned char* const kbase = smem + KOFF + (unsigned)pb * 32768u;
        unsigned char* const vbase = smem + VOFF + (unsigned)pb * 32768u;

        // ---- swapped QK^T: S^T[kv 32][q 32] per wave ----
        f32x4 s[2][2];   // [m (kv16)][n (q16)]
        s[0][0] = (f32x4)0.f; s[0][1] = (f32x4)0.f;
        s[1][0] = (f32x4)0.f; s[1][1] = (f32x4)0.f;
        __builtin_amdgcn_s_setprio(1);
        #pragma unroll
        for (int ks = 0; ks < 4; ++ks) {
            #pragma unroll
            for (int m = 0; m < 2; ++m) {
                f16x8 kf = *(const f16x8*)(kbase
                    + (unsigned)(wk * 32 + m * 16 + c) * 256u
                    + (unsigned)(((4 * ks + g) ^ (c & 7)) * 16));
                s[m][0] = __builtin_amdgcn_mfma_f32_16x16x32_f16(kf, qf[0][ks], s[m][0], 0, 0, 0);
                s[m][1] = __builtin_amdgcn_mfma_f32_16x16x32_f16(kf, qf[1][ks], s[m][1], 0, 0, 0);
            }
        }
        __builtin_amdgcn_s_setprio(0);

        // ---- V frags hoisted to registers NOW: LDS-read latency hides under softmax ----
        // (V data for tile t is valid in vbase all iteration; staging writes go to pb^1)
        f16x8 vr[8];
        #pragma unroll
        for (int df = 0; df < 8; ++df)
            vr[df] = *(const f16x8*)(vbase
                + (unsigned)(df * 16 + c) * 256u
                + (unsigned)(((4 * wk + g) ^ (c & 7)) * 16));

        // ---- lane-local softmax max (per q-row = 16n + c) ----
        float mt[2];
        #pragma unroll
        for (int n = 0; n < 2; ++n) {
            float a0 = fmaxf(fmaxf(s[0][n][0], s[0][n][1]), fmaxf(s[0][n][2], s[0][n][3]));
            float a1 = fmaxf(fmaxf(s[1][n][0], s[1][n][1]), fmaxf(s[1][n][2], s[1][n][3]));
            float v  = fmaxf(a0, a1);
            v = fmaxf(v, __shfl_xor(v, 16, 64));
            v = fmaxf(v, __shfl_xor(v, 32, 64));
            mt[n] = v;
        }

        // ---- defer-max: rescale only when the running max grows past THR ----
        bool need = (mt[0] > m_run[0] + DEFER_THR) || (mt[1] > m_run[1] + DEFER_THR);
        if (__any(need)) {
            float al[2];
            #pragma unroll
            for (int n = 0; n < 2; ++n) {
                float mn = fmaxf(m_run[n], mt[n]);
                al[n] = __builtin_amdgcn_exp2f(m_run[n] - mn);
                m_run[n] = mn;
            }
            float alo[2][4];
            #pragma unroll
            for (int n = 0; n < 2; ++n)
                #pragma unroll
                for (int r = 0; r < 4; ++r)
                    alo[n][r] = __shfl(al[n], 4 * g + r, 16);
            #pragma unroll
            for (int n = 0; n < 2; ++n)
                #pragma unroll
                for (int f = 0; f < 9; ++f)
                    #pragma unroll
                    for (int r = 0; r < 4; ++r) o[n][f][r] *= alo[n][r];
        }

        // ---- P = exp2(S^T - m), packed b64 stores: P[q = 16n+c][kv = 16m+4g .. +3] ----
        #pragma unroll
        for (int n = 0; n < 2; ++n)
            #pragma unroll
            for (int m = 0; m < 2; ++m) {
                f16x4 h;
                #pragma unroll
                for (int r = 0; r < 4; ++r)
                    h[r] = (f16)__builtin_amdgcn_exp2f(s[m][n][r] - m_run[n]);
                *(f16x4*)(pmine + (unsigned)(16 * n + c) * 80u + (unsigned)(32 * m + 8 * g)) = h;
            }

        // ---- PV: O[32 q][128 d] += P[32 q][32 kv] * V[32 kv][128 d] (V from registers) ----
        f16x8 pa[2];
        pa[0] = *(const f16x8*)(pmine + (unsigned)(c) * 80u + 16u * g);
        pa[1] = *(const f16x8*)(pmine + (unsigned)(16 + c) * 80u + 16u * g);
        __builtin_amdgcn_s_setprio(1);
        #pragma unroll
        for (int df = 0; df < 8; ++df) {
            o[0][df] = __builtin_amdgcn_mfma_f32_16x16x32_f16(pa[0], vr[df], o[0][df], 0, 0, 0);
            o[1][df] = __builtin_amdgcn_mfma_f32_16x16x32_f16(pa[1], vr[df], o[1][df], 0, 0, 0);
        }
        o[0][8] = __builtin_amdgcn_mfma_f32_16x16x32_f16(pa[0], onesf, o[0][8], 0, 0, 0);
        o[1][8] = __builtin_amdgcn_mfma_f32_16x16x32_f16(pa[1], onesf, o[1][8], 0, 0, 0);
        __builtin_amdgcn_s_setprio(0);

        __syncthreads();
    }

    // ship final m to O domain (q = 16n + 4g + r)
    float m_o[2][4];
    #pragma unroll
    for (int n = 0; n < 2; ++n)
        #pragma unroll
        for (int r = 0; r < 4; ++r)
            m_o[n][r] = __shfl(m_run[n], 4 * g + r, 16);

    // ---- merge the 4 kv-splits (per wq) via LDS ----
    float* const mld  = (float*)(smem + MOFF);
    float* const lld  = (float*)(smem + LOFF);
    float* const olds = (float*)smem;

    if (wk > 0) {
        const int base = (wq * 3 + (wk - 1)) * 32;
        #pragma unroll
        for (int n = 0; n < 2; ++n)
            #pragma unroll
            for (int f = 0; f < 8; ++f)
                #pragma unroll
                for (int r = 0; r < 4; ++r)
                    olds[(size_t)(base + n * 16 + 4 * g + r) * 132 + f * 16 + c] = o[n][f][r];
        if (c == 0) {
            #pragma unroll
            for (int n = 0; n < 2; ++n)
                #pragma unroll
                for (int r = 0; r < 4; ++r) {
                    mld[(wq * 4 + wk) * 32 + n * 16 + 4 * g + r] = m_o[n][r];
                    lld[(wq * 4 + wk) * 32 + n * 16 + 4 * g + r] = o[n][8][r];
                }
        }
    }
    __syncthreads();

    if (wk == 0) {
        #pragma unroll
        for (int n = 0; n < 2; ++n) {
            #pragma unroll
            for (int r = 0; r < 4; ++r) {
                const int rl = n * 16 + 4 * g + r;
                const float m0 = m_o[n][r];
                const float m1 = mld[(wq * 4 + 1) * 32 + rl];
                const float m2 = mld[(wq * 4 + 2) * 32 + rl];
                const float m3 = mld[(wq * 4 + 3) * 32 + rl];
                const float ms = fmaxf(fmaxf(m0, m1), fmaxf(m2, m3));
                const float a0 = __builtin_amdgcn_exp2f(m0 - ms);
                const float a1 = __builtin_amdgcn_exp2f(m1 - ms);
                const float a2 = __builtin_amdgcn_exp2f(m2 - ms);
                const float a3 = __builtin_amdgcn_exp2f(m3 - ms);
                const float ls = a0 * o[n][8][r]
                               + a1 * lld[(wq * 4 + 1) * 32 + rl]
                               + a2 * lld[(wq * 4 + 2) * 32 + rl]
                               + a3 * lld[(wq * 4 + 3) * 32 + rl];
                const float inv = 1.0f / ls;
                float* orow = out + ((size_t)bb * SEQ + q0 + wq * 32 + rl) * DQK;
                #pragma unroll
                for (int f = 0; f < 8; ++f) {
                    float v = a0 * o[n][f][r]
                            + a1 * olds[(size_t)((wq * 3 + 0) * 32 + rl) * 132 + f * 16 + c]
                            + a2 * olds[(size_t)((wq * 3 + 1) * 32 + rl) * 132 + f * 16 + c]
                            + a3 * olds[(size_t)((wq * 3 + 2) * 32 + rl) * 132 + f * 16 + c];
                    orow[f * 16 + c] = v * inv;
                }
            }
        }
    }
}

extern "C" void kernel_launch(void* const* d_in, const int* in_sizes, int n_in,
                              void* d_out, int out_size, void* d_ws, size_t ws_size,
                              hipStream_t stream) {
    const float* x  = (const float*)d_in[0];
    const float* Wq = (const float*)d_in[1];
    const float* bq = (const float*)d_in[2];
    const float* Wk = (const float*)d_in[3];
    const float* bk = (const float*)d_in[4];
    const float* Wv = (const float*)d_in[5];
    const float* bv = (const float*)d_in[6];
    float* outp = (float*)d_out;

    f16*   qf    = (f16*)d_ws;
    f16*   kf    = qf + (size_t)BATCH * SEQ * DQK;
    f16*   vt    = kf + (size_t)BATCH * SEQ * DQK;
    f16*   wt    = vt + (size_t)BATCH * DQK * SEQ;
    float* biasf = (float*)(wt + (size_t)384 * DM);

    wcvt_kernel<<<96, 256, 0, stream>>>(Wq, bq, Wk, bk, Wv, bv, wt, biasf);

    proj_kernel<<<BATCH * SEQ / 64, 512, 0, stream>>>(x, wt, biasf, qf, kf, vt);

    attn_kernel<<<256, 512, 0, stream>>>(qf, kf, vt, outp);
}